// Round 3
// baseline (284.694 us; speedup 1.0000x reference)
//
#include <hip/hip_runtime.h>
#include <hip/hip_bf16.h>
#include <math.h>

#define Tn   8192
#define Hn   1024
#define En   8
#define DFFn 4096

typedef __attribute__((ext_vector_type(8))) short bf16x8;           // 8 bf16 = 4 VGPRs
typedef __attribute__((ext_vector_type(8))) unsigned short u16x8;   // 16 B
typedef __attribute__((ext_vector_type(4))) float f32x4;

static __device__ inline unsigned short f2bf(float f) {
    __hip_bfloat16 h = __float2bfloat16(f);
    return __builtin_bit_cast(unsigned short, h);
}

// ---------------- prep ----------------------------------------------------
// blocks [0,256):    W1 [1024x4096] -> W1t [4096][1024] bf16, 128x128 tiles
// blocks [256,512):  W2 [4096][1024] -> W2t [1024][4096] bf16, 128x128 tiles
// blocks [512,1536): gate scores + top-2 softmax sum + x->bf16 cast
// Transpose: fat blocks (64KB read each) instead of 8192 4KB blocks.
// LDS tile [128][128] ushort with XOR swizzle col' = col ^ (((row>>3)&7)<<2):
//  - writes: ushort4, conflict-free (each bank 4 touches for b64 = minimum)
//  - reads:  u16 column gather, kg varies per lane -> 8 banks, 2-way (free)
__global__ __launch_bounds__(256) void prep(
    const float* __restrict__ W1, unsigned short* __restrict__ W1t,
    const float* __restrict__ W2, unsigned short* __restrict__ W2t,
    const float* __restrict__ x, const float* __restrict__ gW,
    const float* __restrict__ gb, unsigned short* __restrict__ xbf,
    float* __restrict__ tokw, float* __restrict__ load_sum,
    int* __restrict__ counts)
{
    __shared__ float smem[8 * 1024 + En];   // gwt[8][1024] | transpose tile
    __shared__ int   s_cnt[En];
    const int tid = threadIdx.x;
    const int id  = blockIdx.x;

    if (id < 512) {  // ---- fat transpose+cast ----
        const float* src; unsigned short* dst; int SR, SC, tb;
        if (id < 256) { src = W1; dst = W1t; SR = Hn;   SC = DFFn; tb = id; }
        else          { src = W2; dst = W2t; SR = DFFn; SC = Hn;   tb = id - 256; }
        const int tcs = SC >> 7;                   // tiles per src row
        const int tr  = tb / tcs, tc = tb - tr * tcs;
        const int r0  = tr << 7, c0 = tc << 7;
        unsigned short* tile = (unsigned short*)smem;   // [128][128] swizzled

        #pragma unroll
        for (int i = 0; i < 16; ++i) {             // 128x128 fp32 in, bf16 to LDS
            int idx = tid + i * 256;
            int r = idx >> 5, c4 = (idx & 31) << 2;
            float4 v = *(const float4*)(src + (size_t)(r0 + r) * SC + c0 + c4);
            int cs = c4 ^ (((r >> 3) & 7) << 2);   // XOR keeps 4-contig (low2 free)
            ushort4 pk;
            pk.x = f2bf(v.x); pk.y = f2bf(v.y);
            pk.z = f2bf(v.z); pk.w = f2bf(v.w);
            *(ushort4*)(tile + r * 128 + cs) = pk;
        }
        __syncthreads();
        #pragma unroll
        for (int i = 0; i < 8; ++i) {              // transposed out, 16B stores
            int idx = tid + i * 256;
            int n = idx >> 4, kg = idx & 15, k0 = kg << 3;
            int s = (kg & 7) << 2;                 // == ((k>>3)&7)<<2 for k0..k0+7
            u16x8 o;
            #pragma unroll
            for (int j = 0; j < 8; ++j)
                o[j] = tile[(k0 + j) * 128 + (n ^ s)];
            *(u16x8*)(dst + (size_t)(c0 + n) * SR + r0 + k0) = o;
        }
        return;
    }

    // ---- gate + x cast; gW staged into LDS transposed [E][H] ----
    const int gid = id - 512;                      // 0..1023
    float* gwt    = smem;                          // 32 KB
    float* s_load = smem + 8 * 1024;
    if (tid < En) { s_load[tid] = 0.f; s_cnt[tid] = 0; }
    #pragma unroll
    for (int i = 0; i < 32; ++i) {                 // 8192 floats, coalesced read
        int f = tid + i * 256;
        gwt[(f & 7) * 1024 + (f >> 3)] = gW[f];
    }
    __syncthreads();

    const int lane = tid & 63;
    const int wv   = tid >> 6;

    for (int tok = gid * 4 + wv; tok < Tn; tok += 4096) {   // 2 toks/wave
        const float4* xr = (const float4*)(x + (size_t)tok * Hn);
        float acc[8] = {0.f,0.f,0.f,0.f,0.f,0.f,0.f,0.f};
        #pragma unroll
        for (int j = 0; j < Hn / 256; ++j) {       // 4 iterations
            int h4 = j * 64 + lane;
            float4 xv = xr[h4];
            ushort4 pk;
            pk.x = f2bf(xv.x); pk.y = f2bf(xv.y);
            pk.z = f2bf(xv.z); pk.w = f2bf(xv.w);
            ((ushort4*)xbf)[(size_t)tok * (Hn / 4) + h4] = pk;
            #pragma unroll
            for (int e = 0; e < 8; ++e) {
                const float4 w = *(const float4*)(gwt + e * 1024 + h4 * 4);
                acc[e] += xv.x * w.x + xv.y * w.y + xv.z * w.z + xv.w * w.w;
            }
        }
        #pragma unroll
        for (int e = 0; e < 8; ++e) {
            float v = acc[e];
            #pragma unroll
            for (int off = 32; off > 0; off >>= 1) v += __shfl_xor(v, off, 64);
            acc[e] = v + gb[e];
        }
        if (lane == 0) {
            #pragma unroll
            for (int e = 0; e < 8; ++e) atomicAdd(&s_load[e], acc[e]);
            int i1 = 0; float v1 = acc[0];
            #pragma unroll
            for (int e = 1; e < 8; ++e) if (acc[e] > v1) { v1 = acc[e]; i1 = e; }
            int i2 = -1; float v2 = -3.0e38f;
            #pragma unroll
            for (int e = 0; e < 8; ++e) if (e != i1 && acc[e] > v2) { v2 = acc[e]; i2 = e; }
            atomicAdd(&s_cnt[i1], 1);
            atomicAdd(&s_cnt[i2], 1);
            float e2 = __expf(v2 - v1);
            float t  = 1.0f + e2;
            tokw[tok] = 1.0f / t + e2 / t;   // softmax(top2).sum()
        }
    }
    __syncthreads();
    if (tid < En) {
        atomicAdd(&load_sum[tid], s_load[tid]);
        atomicAdd(&counts[tid],   s_cnt[tid]);
    }
}

// =================== phase-scheduled 256-wide GEMM ========================
// C = epilogue(A @ Bt^T + bias); A:[M][K] bf16 row-major, Bt:[N][K] bf16.
// BM=256, BK=64, 512 thr = 8 waves. Double-buffered LDS, global_load_lds
// width-16 staging, counted vmcnt (never 0 in loop), XOR slot-swizzle on
// the GLOBAL source + ds_read addr (SQ_LDS_BANK_CONFLICT==0 verified r1).
//
// G0 (BN=256, WM=2, WN=4, EPI=0): 8 phases / 2 K-tiles, 16 MFMA/phase,
//   UNSWAPPED mfma(af,bfr) + scalar-store epilogue (r2 showed the swapped
//   vector epilogue regresses gemm0 by 3.7%).
//   TPB=2 persistence: each block does tiles id and id+256 (same n0 ->
//   tile2's B-panel L2-hot). Transition ledger (per-wave FIFO):
//     loop end: <=6 stale clamped loads -> vmcnt(0) (L2-hot, cheap)
//     [bias 16 loads][prologue 14 loads][epilogue 32 stores]
//     vmcnt(38): oldest 24 retired => bias + buf0's 8 landed; stores float
//     barrier -> tile2 loop; first P3 vmcnt(6) absorbs store drain.
// G1 (BN=128, WM=4, WN=2, EPI=1): 4 phases / 2 K-tiles, 16 MFMA/phase,
//   swapped operands + float4 epilogue (r2 form). TPB=1.
static __device__ inline bf16x8 ldsfrag(const char* base, int row, int chunk) {
    return *(const bf16x8*)(base + row * 128 + (((chunk) ^ (row & 7)) << 4));
}

template<int BN, int WM, int WN, int EPI, int TPB>
__global__ __launch_bounds__(512, 2) void gemm8(
    const __hip_bfloat16* __restrict__ A,
    const __hip_bfloat16* __restrict__ Bt,
    const float* __restrict__ bias,
    const float* __restrict__ tokw,
    void* __restrict__ C, int N, int K, int nx,
    const float* __restrict__ load_sum, const int* __restrict__ counts,
    float* __restrict__ out_tail, int nblk)
{
    constexpr int BM = 256;
    constexpr int MR = (BM / WM) / 16;        // 8 (G0) or 4 (G1)
    constexpr int NR = (BN / WN) / 16;        // 4
    constexpr int AU = BM / 64;               // 4 stage units (8 KB each)
    constexpr int BU = BN / 64;               // 4 (G0) or 2 (G1)
    constexpr int ABYTES = BM * 64 * 2;       // 32 KB
    constexpr int BBYTES = BN * 64 * 2;       // 32/16 KB
    constexpr int TILEB  = ABYTES + BBYTES;   // per K-tile buffer

    extern __shared__ char lds[];

    const int tid = threadIdx.x;
    const int id  = blockIdx.x;

    if (EPI == 0 && id >= nblk) {   // ---- aux-loss / counts tail block ----
        if (tid == 0) {
            float aux = 0.f;
            #pragma unroll
            for (int e = 0; e < En; ++e) {
                float m = load_sum[e] * (1.0f / (float)Tn);
                aux += m * m;
            }
            out_tail[0] = aux;
            #pragma unroll
            for (int e = 0; e < En; ++e) out_tail[1 + e] = (float)counts[e];
        }
        return;
    }

    const int lane = tid & 63;
    const int wid  = tid >> 6;
    const int wn   = wid % WN;
    const int wm   = wid / WN;
    const int wrow = wm * (BM / WM);
    const int wcol = wn * (BN / WN);
    const int fr   = lane & 15;
    const int fq   = lane >> 4;

    // staging map: thread t covers LDS (row=t>>3, slot=t&7) of one unit;
    // source k-chunk pre-swizzled so ds_read applies the same XOR.
    const int sr = tid >> 3;                 // 0..63
    const int sc = (tid & 7) ^ (sr & 7);     // global k-chunk (8 bf16)

    int m0, n0;
    unsigned aOff[AU], bOff[BU];
    auto setup = [&](int t) {
        // bijective XCD swizzle over nblk*TPB tiles (both instantiations %8==0)
        int g   = id + t * nblk;
        int xcd = g & 7;
        int wg  = xcd * ((nblk * TPB) >> 3) + (g >> 3);
        int by  = wg / nx, bx = wg - by * nx;
        m0 = by * BM; n0 = bx * BN;
        #pragma unroll
        for (int u = 0; u < AU; ++u)
            aOff[u] = (unsigned)((m0 + u * 64 + sr) * K + sc * 8);
        #pragma unroll
        for (int u = 0; u < BU; ++u)
            bOff[u] = (unsigned)((n0 + u * 64 + sr) * K + sc * 8);
    };
    setup(0);

#define STA(b, u, kt) __builtin_amdgcn_global_load_lds( \
    (const __attribute__((address_space(1))) void*)(A + aOff[u] + (unsigned)(kt) * 64u), \
    (__attribute__((address_space(3))) void*)(lds + (b) * TILEB + (u) * 8192 + tid * 16), 16, 0, 0)
#define STB(b, u, kt) __builtin_amdgcn_global_load_lds( \
    (const __attribute__((address_space(1))) void*)(Bt + bOff[u] + (unsigned)(kt) * 64u), \
    (__attribute__((address_space(3))) void*)(lds + (b) * TILEB + ABYTES + (u) * 8192 + tid * 16), 16, 0, 0)

#define PROLOG_G0 do { \
    STA(0,0,0); STA(0,1,0); STA(0,2,0); STA(0,3,0); \
    STB(0,0,0); STB(0,1,0); STB(0,2,0); STB(0,3,0); \
    STA(1,0,1); STA(1,2,1); \
    STB(1,0,1); STB(1,1,1); STB(1,2,1); STB(1,3,1); } while (0)

    bf16x8 af[MR / 2][2];
    bf16x8 bfr[4][2];
    f32x4  acc[MR][NR];
    const f32x4 zero = {0.f, 0.f, 0.f, 0.f};
    #pragma unroll
    for (int i = 0; i < MR; ++i)
        #pragma unroll
        for (int j = 0; j < NR; ++j) acc[i][j] = zero;

#define RDA(b, half) do { _Pragma("unroll") \
    for (int m_ = 0; m_ < MR / 2; ++m_) { _Pragma("unroll") \
        for (int ks_ = 0; ks_ < 2; ++ks_) \
            af[m_][ks_] = ldsfrag(lds + (b) * TILEB, \
                wrow + ((half) * (MR / 2) + m_) * 16 + fr, ks_ * 4 + fq); } } while (0)

#define RDB(b, half) do { _Pragma("unroll") \
    for (int n_ = 0; n_ < 2; ++n_) { _Pragma("unroll") \
        for (int ks_ = 0; ks_ < 2; ++ks_) \
            bfr[(half) * 2 + n_][ks_] = ldsfrag(lds + (b) * TILEB + ABYTES, \
                wcol + ((half) * 2 + n_) * 16 + fr, ks_ * 4 + fq); } } while (0)

// G0: one (hm,hn) C-quadrant, 16 MFMA, UNSWAPPED (r1 form).
#define MFMAQ(hm, hn) do { \
    __builtin_amdgcn_s_setprio(1); \
    _Pragma("unroll") \
    for (int m_ = 0; m_ < MR / 2; ++m_) { _Pragma("unroll") \
        for (int n_ = 0; n_ < 2; ++n_) { _Pragma("unroll") \
            for (int ks_ = 0; ks_ < 2; ++ks_) \
                acc[(hm) * (MR / 2) + m_][(hn) * 2 + n_] = \
                    __builtin_amdgcn_mfma_f32_16x16x32_bf16( \
                        af[m_][ks_], bfr[(hn) * 2 + n_][ks_], \
                        acc[(hm) * (MR / 2) + m_][(hn) * 2 + n_], 0, 0, 0); } } \
    __builtin_amdgcn_s_setprio(0); } while (0)

// G1: one hm half across ALL n, 16 MFMA, SWAPPED (r2 form).
#define MFMAQ1(hm) do { \
    __builtin_amdgcn_s_setprio(1); \
    _Pragma("unroll") \
    for (int m_ = 0; m_ < MR / 2; ++m_) { _Pragma("unroll") \
        for (int n_ = 0; n_ < NR; ++n_) { _Pragma("unroll") \
            for (int ks_ = 0; ks_ < 2; ++ks_) \
                acc[(hm) * (MR / 2) + m_][n_] = \
                    __builtin_amdgcn_mfma_f32_16x16x32_bf16( \
                        bfr[n_][ks_], af[m_][ks_], \
                        acc[(hm) * (MR / 2) + m_][n_], 0, 0, 0); } } \
    __builtin_amdgcn_s_setprio(0); } while (0)

#define MIDSYNC do { \
    __builtin_amdgcn_sched_barrier(0); \
    __builtin_amdgcn_s_barrier(); \
    asm volatile("s_waitcnt lgkmcnt(0)" ::: "memory"); \
    __builtin_amdgcn_sched_barrier(0); } while (0)

#define ENDBAR do { \
    __builtin_amdgcn_sched_barrier(0); \
    __builtin_amdgcn_s_barrier(); \
    __builtin_amdgcn_sched_barrier(0); } while (0)

#define DRAIN6 do { asm volatile("s_waitcnt vmcnt(6)" ::: "memory"); \
    __builtin_amdgcn_sched_barrier(0); } while (0)
#define DRAIN2 do { asm volatile("s_waitcnt vmcnt(2)" ::: "memory"); \
    __builtin_amdgcn_sched_barrier(0); } while (0)

    const int KT = K >> 6;   // K-tiles of 64

    if constexpr (WM == 2) {
        // ================= G0: 8-phase, TPB tiles per block =================
        PROLOG_G0;
        DRAIN6;
        __builtin_amdgcn_s_barrier();
        __builtin_amdgcn_sched_barrier(0);

        for (int tt = 0; tt < TPB; ++tt) {
            for (int i = 0; i < (KT >> 1); ++i) {
                const int t1 = 2 * i + 1;
                const int c2 = (2 * i + 2 < KT) ? 2 * i + 2 : KT - 1;
                const int c3 = (2 * i + 3 < KT) ? 2 * i + 3 : KT - 1;

                // P0: tile 2i quadrant (0,0)
                RDA(0, 0); RDB(0, 0);
                STA(1,1,t1); STA(1,3,t1);
                MIDSYNC; MFMAQ(0, 0); ENDBAR;
                // P1
                RDB(0, 1);
                STA(0,0,c2); STA(0,2,c2);
                MIDSYNC; MFMAQ(0, 1); ENDBAR;
                // P2
                RDA(0, 1);
                STB(0,0,c2); STB(0,1,c2);
                MIDSYNC; MFMAQ(1, 0); ENDBAR;
                // P3; drain -> tile 2i+1 fully in LDS
                STB(0,2,c2); STB(0,3,c2);
                MIDSYNC; MFMAQ(1, 1); DRAIN6; ENDBAR;
                // P4: tile 2i+1 quadrant (0,0)
                RDA(1, 0); RDB(1, 0);
                STA(0,1,c2); STA(0,3,c2);
                MIDSYNC; MFMAQ(0, 0); ENDBAR;
                // P5
                RDB(1, 1);
                STA(1,0,c3); STA(1,2,c3);
                MIDSYNC; MFMAQ(0, 1); ENDBAR;
                // P6
                RDA(1, 1);
                STB(1,0,c3); STB(1,1,c3);
                MIDSYNC; MFMAQ(1, 0); ENDBAR;
                // P7; drain -> tile 2i+2 fully in LDS
                STB(1,2,c3); STB(1,3,c3);
                MIDSYNC; MFMAQ(1, 1); DRAIN6; ENDBAR;
            }

            const int em0 = m0, en0 = n0;
            if (tt + 1 < TPB) {
                // stale clamped stages retired before LDS re-stage (same slots)
                asm volatile("s_waitcnt vmcnt(0)" ::: "memory");
                __builtin_amdgcn_sched_barrier(0);
            }
            float bias4[NR];
            #pragma unroll
            for (int ni = 0; ni < NR; ++ni)
                bias4[ni] = bias[en0 + wcol + ni * 16 + fr];
            if (tt + 1 < TPB) {
                setup(tt + 1);
                PROLOG_G0;               // next tile's fill overlaps epilogue
            }
            // epilogue: C/D layout col = lane&15, row = (lane>>4)*4 + reg
            #pragma unroll
            for (int mi = 0; mi < MR; ++mi) {
                #pragma unroll
                for (int ni = 0; ni < NR; ++ni) {
                    const int col = en0 + wcol + ni * 16 + fr;
                    const int rb  = em0 + wrow + mi * 16 + fq * 4;
                    #pragma unroll
                    for (int i2 = 0; i2 < 4; ++i2) {
                        float u  = acc[mi][ni][i2] + bias4[ni];
                        float uu = u * u;
                        float z  = u * __fmaf_rn(uu, -0.07135607f, -1.59576912f);
                        float e  = __expf(z);            // e^{-2s}
                        float g  = u * __builtin_amdgcn_rcpf(1.0f + e);
                        ((__hip_bfloat16*)C)[(size_t)(rb + i2) * N + col] =
                            __float2bfloat16(g);
                    }
                }
            }
            if (tt + 1 < TPB) {
                #pragma unroll
                for (int i = 0; i < MR; ++i)
                    #pragma unroll
                    for (int j = 0; j < NR; ++j) acc[i][j] = zero;
                // FIFO [bias16][L14][S32]: <=38 => bias + buf0's 8 landed
                asm volatile("s_waitcnt vmcnt(38)" ::: "memory");
                __builtin_amdgcn_sched_barrier(0);
                __builtin_amdgcn_s_barrier();
                __builtin_amdgcn_sched_barrier(0);
            }
        }
    } else {
        // ================= G1: 4-phase, single tile =================
        STA(0,0,0); STA(0,1,0); STA(0,2,0); STA(0,3,0);
        STB(0,0,0); STB(0,1,0);
        STB(1,0,1); STB(1,1,1);
        DRAIN2;
        __builtin_amdgcn_s_barrier();
        __builtin_amdgcn_sched_barrier(0);

        for (int i = 0; i < (KT >> 1); ++i) {
            const int t1 = 2 * i + 1;
            const int c2 = (2 * i + 2 < KT) ? 2 * i + 2 : KT - 1;
            const int c3 = (2 * i + 3 < KT) ? 2 * i + 3 : KT - 1;

            // P0: read buf0 {A-half0, B-full}; stage buf1.A0-3 (tile 2i+1)
            RDA(0, 0); RDB(0, 0); RDB(0, 1);
            STA(1,0,t1); STA(1,1,t1); STA(1,2,t1); STA(1,3,t1);
            MIDSYNC; MFMAQ1(0); ENDBAR;
            // P1: read buf0 A-half1; stage buf0.B01 (tile 2i+2); drain(2)
            RDA(0, 1);
            STB(0,0,c2); STB(0,1,c2);
            MIDSYNC; MFMAQ1(1); DRAIN2; ENDBAR;
            // P2: read buf1 {A-half0, B-full}; stage buf0.A0-3 (tile 2i+2)
            RDA(1, 0); RDB(1, 0); RDB(1, 1);
            STA(0,0,c2); STA(0,1,c2); STA(0,2,c2); STA(0,3,c2);
            MIDSYNC; MFMAQ1(0); ENDBAR;
            // P3: read buf1 A-half1; stage buf1.B01 (tile 2i+3); drain(2)
            RDA(1, 1);
            STB(1,0,c3); STB(1,1,c3);
            MIDSYNC; MFMAQ1(1); DRAIN2; ENDBAR;
        }

        // epilogue (swapped D): M = lane&15, N = (lane>>4)*4+reg -> float4
        const int mrow0 = m0 + wrow + fr;
        const int ncol0 = n0 + wcol + fq * 4;
        float4 b4[NR];
        #pragma unroll
        for (int ni = 0; ni < NR; ++ni)
            b4[ni] = *(const float4*)(bias + ncol0 + ni * 16);

        #pragma unroll
        for (int mi = 0; mi < MR; ++mi) {
            const int row = mrow0 + mi * 16;
            const float tw = tokw[row];
            #pragma unroll
            for (int ni = 0; ni < NR; ++ni) {
                f32x4 v = acc[mi][ni];
                float4 o;
                o.x = (v[0] + b4[ni].x) * tw;
                o.y = (v[1] + b4[ni].y) * tw;
                o.z = (v[2] + b4[ni].z) * tw;
                o.w = (v[3] + b4[ni].w) * tw;
                *(float4*)((float*)C + (size_t)row * N + ncol0 + ni * 16) = o;
            }
        }
    }

#undef STA
#undef STB
#undef PROLOG_G0
#undef RDA
#undef RDB
#undef MFMAQ
#undef MFMAQ1
#undef MIDSYNC
#undef ENDBAR
#undef DRAIN6
#undef DRAIN2
}

extern "C" void kernel_launch(void* const* d_in, const int* in_sizes, int n_in,
                              void* d_out, int out_size, void* d_ws, size_t ws_size,
                              hipStream_t stream)
{
    const float* x  = (const float*)d_in[0];
    const float* gW = (const float*)d_in[1];
    const float* gb = (const float*)d_in[2];
    const float* W1 = (const float*)d_in[3];
    const float* b1 = (const float*)d_in[4];
    const float* W2 = (const float*)d_in[5];
    const float* b2 = (const float*)d_in[6];
    float* out = (float*)d_out;

    char* ws = (char*)d_ws;
    __hip_bfloat16* xbf = (__hip_bfloat16*)ws;  ws += (size_t)Tn * Hn * 2;     // 16 MB
    __hip_bfloat16* W1t = (__hip_bfloat16*)ws;  ws += (size_t)Hn * DFFn * 2;   //  8 MB
    __hip_bfloat16* W2t = (__hip_bfloat16*)ws;  ws += (size_t)Hn * DFFn * 2;   //  8 MB
    __hip_bfloat16* hdd = (__hip_bfloat16*)ws;  ws += (size_t)Tn * DFFn * 2;   // 64 MB
    float* tokw     = (float*)ws;               ws += (size_t)Tn * 4;          // 32 KB
    float* load_sum = (float*)ws;               ws += En * 4;
    int*   counts   = (int*)ws;                 ws += En * 4;

    static bool attr_done = false;
    if (!attr_done) {
        (void)hipFuncSetAttribute(
            reinterpret_cast<const void*>(&gemm8<256, 2, 4, 0, 2>),
            hipFuncAttributeMaxDynamicSharedMemorySize, 131072);
        (void)hipFuncSetAttribute(
            reinterpret_cast<const void*>(&gemm8<128, 4, 2, 1, 1>),
            hipFuncAttributeMaxDynamicSharedMemorySize, 98304);
        attr_done = true;
    }

    hipMemsetAsync(load_sum, 0, En * 4 * 2, stream);   // load_sum + counts

    // 512 fat transpose blocks + 1024 gate blocks
    prep<<<1536, 256, 0, stream>>>(W1, (unsigned short*)W1t,
                                   W2, (unsigned short*)W2t,
                                   x, gW, gb, (unsigned short*)xbf,
                                   tokw, load_sum, counts);

    // hdd = gelu(x @ W1 + b1): M=8192, N=4096, K=1024
    // 256 persistent blocks x 2 tiles (32x16 = 512 tiles) + 1 aux block
    gemm8<256, 2, 4, 0, 2><<<257, 512, 131072, stream>>>(
        xbf, W1t, b1, nullptr, hdd, DFFn, Hn, 16,
        load_sum, counts, out + (size_t)Tn * Hn, 256);

    // out = (hdd @ W2 + b2) * tokw: M=8192, N=1024, K=4096; 32x8 = 256 blocks
    gemm8<128, 4, 2, 1, 1><<<256, 512, 98304, stream>>>(
        hdd, W2t, b2, tokw, out, Hn, DFFn, 8,
        nullptr, nullptr, nullptr, 256);
}

// Round 4
// 267.725 us; speedup vs baseline: 1.0634x; 1.0634x over previous
//
#include <hip/hip_runtime.h>
#include <hip/hip_bf16.h>
#include <math.h>

#define Tn   8192
#define Hn   1024
#define En   8
#define DFFn 4096

typedef __attribute__((ext_vector_type(8))) short bf16x8;           // 8 bf16 = 4 VGPRs
typedef __attribute__((ext_vector_type(8))) unsigned short u16x8;   // 16 B
typedef __attribute__((ext_vector_type(4))) float f32x4;

static __device__ inline unsigned short f2bf(float f) {
    __hip_bfloat16 h = __float2bfloat16(f);
    return __builtin_bit_cast(unsigned short, h);
}

// ---------------- prep ----------------------------------------------------
// blocks [0,256):    W1 [1024x4096] -> W1t [4096][1024] bf16, 128x128 tiles
// blocks [256,512):  W2 [4096][1024] -> W2t [1024][4096] bf16, 128x128 tiles
// blocks [512,1536): gate scores + top-2 softmax sum + x->bf16 cast
__global__ __launch_bounds__(256) void prep(
    const float* __restrict__ W1, unsigned short* __restrict__ W1t,
    const float* __restrict__ W2, unsigned short* __restrict__ W2t,
    const float* __restrict__ x, const float* __restrict__ gW,
    const float* __restrict__ gb, unsigned short* __restrict__ xbf,
    float* __restrict__ tokw, float* __restrict__ load_sum,
    int* __restrict__ counts)
{
    __shared__ float smem[8 * 1024 + En];   // gwt[8][1024] | transpose tile
    __shared__ int   s_cnt[En];
    const int tid = threadIdx.x;
    const int id  = blockIdx.x;

    if (id < 512) {  // ---- fat transpose+cast ----
        const float* src; unsigned short* dst; int SR, SC, tb;
        if (id < 256) { src = W1; dst = W1t; SR = Hn;   SC = DFFn; tb = id; }
        else          { src = W2; dst = W2t; SR = DFFn; SC = Hn;   tb = id - 256; }
        const int tcs = SC >> 7;                   // tiles per src row
        const int tr  = tb / tcs, tc = tb - tr * tcs;
        const int r0  = tr << 7, c0 = tc << 7;
        unsigned short* tile = (unsigned short*)smem;   // [128][128] swizzled

        #pragma unroll
        for (int i = 0; i < 16; ++i) {             // 128x128 fp32 in, bf16 to LDS
            int idx = tid + i * 256;
            int r = idx >> 5, c4 = (idx & 31) << 2;
            float4 v = *(const float4*)(src + (size_t)(r0 + r) * SC + c0 + c4);
            int cs = c4 ^ (((r >> 3) & 7) << 2);   // XOR keeps 4-contig
            ushort4 pk;
            pk.x = f2bf(v.x); pk.y = f2bf(v.y);
            pk.z = f2bf(v.z); pk.w = f2bf(v.w);
            *(ushort4*)(tile + r * 128 + cs) = pk;
        }
        __syncthreads();
        #pragma unroll
        for (int i = 0; i < 8; ++i) {              // transposed out, 16B stores
            int idx = tid + i * 256;
            int n = idx >> 4, kg = idx & 15, k0 = kg << 3;
            int s = (kg & 7) << 2;
            u16x8 o;
            #pragma unroll
            for (int j = 0; j < 8; ++j)
                o[j] = tile[(k0 + j) * 128 + (n ^ s)];
            *(u16x8*)(dst + (size_t)(c0 + n) * SR + r0 + k0) = o;
        }
        return;
    }

    // ---- gate + x cast; gW staged into LDS transposed [E][H] ----
    const int gid = id - 512;                      // 0..1023
    float* gwt    = smem;                          // 32 KB
    float* s_load = smem + 8 * 1024;
    if (tid < En) { s_load[tid] = 0.f; s_cnt[tid] = 0; }
    #pragma unroll
    for (int i = 0; i < 32; ++i) {                 // 8192 floats, coalesced read
        int f = tid + i * 256;
        gwt[(f & 7) * 1024 + (f >> 3)] = gW[f];
    }
    __syncthreads();

    const int lane = tid & 63;
    const int wv   = tid >> 6;

    for (int tok = gid * 4 + wv; tok < Tn; tok += 4096) {   // 2 toks/wave
        const float4* xr = (const float4*)(x + (size_t)tok * Hn);
        float acc[8] = {0.f,0.f,0.f,0.f,0.f,0.f,0.f,0.f};
        #pragma unroll
        for (int j = 0; j < Hn / 256; ++j) {       // 4 iterations
            int h4 = j * 64 + lane;
            float4 xv = xr[h4];
            ushort4 pk;
            pk.x = f2bf(xv.x); pk.y = f2bf(xv.y);
            pk.z = f2bf(xv.z); pk.w = f2bf(xv.w);
            ((ushort4*)xbf)[(size_t)tok * (Hn / 4) + h4] = pk;
            #pragma unroll
            for (int e = 0; e < 8; ++e) {
                const float4 w = *(const float4*)(gwt + e * 1024 + h4 * 4);
                acc[e] += xv.x * w.x + xv.y * w.y + xv.z * w.z + xv.w * w.w;
            }
        }
        #pragma unroll
        for (int e = 0; e < 8; ++e) {
            float v = acc[e];
            #pragma unroll
            for (int off = 32; off > 0; off >>= 1) v += __shfl_xor(v, off, 64);
            acc[e] = v + gb[e];
        }
        if (lane == 0) {
            #pragma unroll
            for (int e = 0; e < 8; ++e) atomicAdd(&s_load[e], acc[e]);
            int i1 = 0; float v1 = acc[0];
            #pragma unroll
            for (int e = 1; e < 8; ++e) if (acc[e] > v1) { v1 = acc[e]; i1 = e; }
            int i2 = -1; float v2 = -3.0e38f;
            #pragma unroll
            for (int e = 0; e < 8; ++e) if (e != i1 && acc[e] > v2) { v2 = acc[e]; i2 = e; }
            atomicAdd(&s_cnt[i1], 1);
            atomicAdd(&s_cnt[i2], 1);
            float e2 = __expf(v2 - v1);
            float t  = 1.0f + e2;
            tokw[tok] = 1.0f / t + e2 / t;   // softmax(top2).sum()
        }
    }
    __syncthreads();
    if (tid < En) {
        atomicAdd(&load_sum[tid], s_load[tid]);
        atomicAdd(&counts[tid],   s_cnt[tid]);
    }
}

// =================== phase-scheduled 256-wide GEMM ========================
// C = epilogue(A @ Bt^T + bias); A:[M][K] bf16 row-major, Bt:[N][K] bf16.
// BM=256, BK=64, 512 thr = 8 waves. Double-buffered LDS, global_load_lds
// width-16 staging, counted vmcnt (never 0 in loop), XOR slot-swizzle on
// global source + ds_read addr (conflict-free, verified r1). TPB reverted
// to 1 (r3: persistence caused +30MB write amplification, +4us).
//
// NEW (r4): counted-lgkmcnt LADDER. Reads are issued in consumption order;
// the MFMA cluster interleaves lgkmcnt(6/4/2/0) so the first MFMAs execute
// while the remaining ds_reads drain (r3 theory: the single lgkmcnt(0)
// serialized a ~400-770cy LDS drain against an idle matrix pipe -> 35%
// MfmaUtil). Each wait is followed by sched_barrier(0) (rule #18).
//
// G0 (BN=256, WM=2, WN=4, EPI=0): 8 phases / 2 K-tiles, 16 MFMA/phase.
//   stage schedule + vmcnt(6) ledger unchanged from r1 (verified).
// G1 (BN=128, WM=4, WN=2, EPI=1): 4 phases / 2 K-tiles, 16 MFMA/phase,
//   swapped operands + float4 epilogue; vmcnt(2) ledger unchanged from r2.
static __device__ inline bf16x8 ldsfrag(const char* base, int row, int chunk) {
    return *(const bf16x8*)(base + row * 128 + (((chunk) ^ (row & 7)) << 4));
}

template<int BN, int WM, int WN, int EPI>
__global__ __launch_bounds__(512, 2) void gemm8(
    const __hip_bfloat16* __restrict__ A,
    const __hip_bfloat16* __restrict__ Bt,
    const float* __restrict__ bias,
    const float* __restrict__ tokw,
    void* __restrict__ C, int N, int K, int nx,
    const float* __restrict__ load_sum, const int* __restrict__ counts,
    float* __restrict__ out_tail, int nblk)
{
    constexpr int BM = 256;
    constexpr int MR = (BM / WM) / 16;        // 8 (G0) or 4 (G1)
    constexpr int NR = (BN / WN) / 16;        // 4
    constexpr int AU = BM / 64;               // 4 stage units (8 KB each)
    constexpr int BU = BN / 64;               // 4 (G0) or 2 (G1)
    constexpr int ABYTES = BM * 64 * 2;       // 32 KB
    constexpr int BBYTES = BN * 64 * 2;       // 32/16 KB
    constexpr int TILEB  = ABYTES + BBYTES;   // per K-tile buffer

    extern __shared__ char lds[];

    const int tid = threadIdx.x;
    const int id  = blockIdx.x;

    if (EPI == 0 && id >= nblk) {   // ---- aux-loss / counts tail block ----
        if (tid == 0) {
            float aux = 0.f;
            #pragma unroll
            for (int e = 0; e < En; ++e) {
                float m = load_sum[e] * (1.0f / (float)Tn);
                aux += m * m;
            }
            out_tail[0] = aux;
            #pragma unroll
            for (int e = 0; e < En; ++e) out_tail[1 + e] = (float)counts[e];
        }
        return;
    }

    // bijective XCD swizzle (nblk % 8 == 0 for both instantiations)
    int wg = id;
    { int xcd = wg & 7, idx = wg >> 3; wg = xcd * (nblk >> 3) + idx; }
    const int by = wg / nx, bx = wg % nx;
    const int m0 = by * BM, n0 = bx * BN;

    const int lane = tid & 63;
    const int wid  = tid >> 6;
    const int wn   = wid % WN;
    const int wm   = wid / WN;
    const int wrow = wm * (BM / WM);
    const int wcol = wn * (BN / WN);
    const int fr   = lane & 15;
    const int fq   = lane >> 4;

    // staging map: thread t covers LDS (row=t>>3, slot=t&7) of one unit;
    // source k-chunk pre-swizzled so ds_read applies the same XOR.
    const int sr = tid >> 3;                 // 0..63
    const int sc = (tid & 7) ^ (sr & 7);     // global k-chunk (8 bf16)
    unsigned aOff[AU], bOff[BU];
    #pragma unroll
    for (int u = 0; u < AU; ++u)
        aOff[u] = (unsigned)((m0 + u * 64 + sr) * K + sc * 8);
    #pragma unroll
    for (int u = 0; u < BU; ++u)
        bOff[u] = (unsigned)((n0 + u * 64 + sr) * K + sc * 8);

#define STA(b, u, kt) __builtin_amdgcn_global_load_lds( \
    (const __attribute__((address_space(1))) void*)(A + aOff[u] + (unsigned)(kt) * 64u), \
    (__attribute__((address_space(3))) void*)(lds + (b) * TILEB + (u) * 8192 + tid * 16), 16, 0, 0)
#define STB(b, u, kt) __builtin_amdgcn_global_load_lds( \
    (const __attribute__((address_space(1))) void*)(Bt + bOff[u] + (unsigned)(kt) * 64u), \
    (__attribute__((address_space(3))) void*)(lds + (b) * TILEB + ABYTES + (u) * 8192 + tid * 16), 16, 0, 0)

    bf16x8 af[MR / 2][2];
    bf16x8 bfr[4][2];
    f32x4  acc[MR][NR];
    const f32x4 zero = {0.f, 0.f, 0.f, 0.f};
    #pragma unroll
    for (int i = 0; i < MR; ++i)
        #pragma unroll
        for (int j = 0; j < NR; ++j) acc[i][j] = zero;

// single-fragment reads (2 ds_read_b128 each), issued in consumption order
#define RD_A1(b, half, m_) do { _Pragma("unroll") \
    for (int ks_ = 0; ks_ < 2; ++ks_) \
        af[m_][ks_] = ldsfrag(lds + (b) * TILEB, \
            wrow + ((half) * (MR / 2) + (m_)) * 16 + fr, ks_ * 4 + fq); } while (0)
#define RD_B1(b, nn) do { _Pragma("unroll") \
    for (int ks_ = 0; ks_ < 2; ++ks_) \
        bfr[nn][ks_] = ldsfrag(lds + (b) * TILEB + ABYTES, \
            wcol + (nn) * 16 + fr, ks_ * 4 + fq); } while (0)

// G0 MFMA slices (unswapped): 4 MFMA for one m-frag over an n-half, or
// 8 MFMA for one n-frag over all m of a half.
#define MFMA_M(hm, hn, m_) do { _Pragma("unroll") \
    for (int n_ = 0; n_ < 2; ++n_) { _Pragma("unroll") \
        for (int ks_ = 0; ks_ < 2; ++ks_) \
            acc[(hm) * (MR / 2) + (m_)][(hn) * 2 + n_] = \
                __builtin_amdgcn_mfma_f32_16x16x32_bf16( \
                    af[m_][ks_], bfr[(hn) * 2 + n_][ks_], \
                    acc[(hm) * (MR / 2) + (m_)][(hn) * 2 + n_], 0, 0, 0); } } while (0)
#define MFMA_N(hm, nn) do { _Pragma("unroll") \
    for (int m_ = 0; m_ < MR / 2; ++m_) { _Pragma("unroll") \
        for (int ks_ = 0; ks_ < 2; ++ks_) \
            acc[(hm) * (MR / 2) + m_][nn] = \
                __builtin_amdgcn_mfma_f32_16x16x32_bf16( \
                    af[m_][ks_], bfr[nn][ks_], \
                    acc[(hm) * (MR / 2) + m_][nn], 0, 0, 0); } } while (0)

// G1 MFMA slices (swapped operands): 4 MFMA for one n over both m of a
// half, or 8 MFMA for one m over all n.
#define MFMA1_N(hm, nn) do { _Pragma("unroll") \
    for (int m_ = 0; m_ < MR / 2; ++m_) { _Pragma("unroll") \
        for (int ks_ = 0; ks_ < 2; ++ks_) \
            acc[(hm) * (MR / 2) + m_][nn] = \
                __builtin_amdgcn_mfma_f32_16x16x32_bf16( \
                    bfr[nn][ks_], af[m_][ks_], \
                    acc[(hm) * (MR / 2) + m_][nn], 0, 0, 0); } } while (0)
#define MFMA1_M(hm, m_) do { _Pragma("unroll") \
    for (int n_ = 0; n_ < NR; ++n_) { _Pragma("unroll") \
        for (int ks_ = 0; ks_ < 2; ++ks_) \
            acc[(hm) * (MR / 2) + (m_)][n_] = \
                __builtin_amdgcn_mfma_f32_16x16x32_bf16( \
                    bfr[n_][ks_], af[m_][ks_], \
                    acc[(hm) * (MR / 2) + (m_)][n_], 0, 0, 0); } } while (0)

#define SBAR do { \
    __builtin_amdgcn_sched_barrier(0); \
    __builtin_amdgcn_s_barrier(); \
    __builtin_amdgcn_sched_barrier(0); } while (0)
#define WAITL(n) do { \
    asm volatile("s_waitcnt lgkmcnt(" #n ")" ::: "memory"); \
    __builtin_amdgcn_sched_barrier(0); } while (0)
#define PRIO1 __builtin_amdgcn_s_setprio(1)
#define PRIO0 __builtin_amdgcn_s_setprio(0)
#define DRAIN6 do { asm volatile("s_waitcnt vmcnt(6)" ::: "memory"); \
    __builtin_amdgcn_sched_barrier(0); } while (0)
#define DRAIN2 do { asm volatile("s_waitcnt vmcnt(2)" ::: "memory"); \
    __builtin_amdgcn_sched_barrier(0); } while (0)

    const int KT = K >> 6;   // K-tiles of 64

    if constexpr (WM == 2) {
        // ================= G0: 8-phase, lgkm ladder =================
        STA(0,0,0); STA(0,1,0); STA(0,2,0); STA(0,3,0);
        STB(0,0,0); STB(0,1,0); STB(0,2,0); STB(0,3,0);
        STA(1,0,1); STA(1,2,1);
        STB(1,0,1); STB(1,1,1); STB(1,2,1); STB(1,3,1);
        DRAIN6;
        __builtin_amdgcn_s_barrier();
        __builtin_amdgcn_sched_barrier(0);

        for (int i = 0; i < (KT >> 1); ++i) {
            const int t1 = 2 * i + 1;
            const int c2 = (2 * i + 2 < KT) ? 2 * i + 2 : KT - 1;
            const int c3 = (2 * i + 3 < KT) ? 2 * i + 3 : KT - 1;

            // P0: Q(0,0) of tile 2i. reads (issue order = consume order):
            // bfr0,bfr1,af0..af3 (12)
            RD_B1(0,0); RD_B1(0,1);
            RD_A1(0,0,0); RD_A1(0,0,1); RD_A1(0,0,2); RD_A1(0,0,3);
            STA(1,1,t1); STA(1,3,t1);
            SBAR; PRIO1;
            WAITL(6); MFMA_M(0,0,0);
            WAITL(4); MFMA_M(0,0,1);
            WAITL(2); MFMA_M(0,0,2);
            WAITL(0); MFMA_M(0,0,3);
            PRIO0; SBAR;
            // P1: Q(0,1). reads bfr2,bfr3 (4)
            RD_B1(0,2); RD_B1(0,3);
            STA(0,0,c2); STA(0,2,c2);
            SBAR; PRIO1;
            WAITL(2); MFMA_N(0,2);
            WAITL(0); MFMA_N(0,3);
            PRIO0; SBAR;
            // P2: Q(1,0). reads af half1 (8)
            RD_A1(0,1,0); RD_A1(0,1,1); RD_A1(0,1,2); RD_A1(0,1,3);
            STB(0,0,c2); STB(0,1,c2);
            SBAR; PRIO1;
            WAITL(6); MFMA_M(1,0,0);
            WAITL(4); MFMA_M(1,0,1);
            WAITL(2); MFMA_M(1,0,2);
            WAITL(0); MFMA_M(1,0,3);
            PRIO0; SBAR;
            // P3: Q(1,1). no reads; drain -> tile 2i+1 fully in LDS
            STB(0,2,c2); STB(0,3,c2);
            SBAR; PRIO1;
            MFMA_M(1,1,0); MFMA_M(1,1,1); MFMA_M(1,1,2); MFMA_M(1,1,3);
            PRIO0; DRAIN6; SBAR;
            // P4: Q(0,0) of tile 2i+1
            RD_B1(1,0); RD_B1(1,1);
            RD_A1(1,0,0); RD_A1(1,0,1); RD_A1(1,0,2); RD_A1(1,0,3);
            STA(0,1,c2); STA(0,3,c2);
            SBAR; PRIO1;
            WAITL(6); MFMA_M(0,0,0);
            WAITL(4); MFMA_M(0,0,1);
            WAITL(2); MFMA_M(0,0,2);
            WAITL(0); MFMA_M(0,0,3);
            PRIO0; SBAR;
            // P5
            RD_B1(1,2); RD_B1(1,3);
            STA(1,0,c3); STA(1,2,c3);
            SBAR; PRIO1;
            WAITL(2); MFMA_N(0,2);
            WAITL(0); MFMA_N(0,3);
            PRIO0; SBAR;
            // P6
            RD_A1(1,1,0); RD_A1(1,1,1); RD_A1(1,1,2); RD_A1(1,1,3);
            STB(1,0,c3); STB(1,1,c3);
            SBAR; PRIO1;
            WAITL(6); MFMA_M(1,0,0);
            WAITL(4); MFMA_M(1,0,1);
            WAITL(2); MFMA_M(1,0,2);
            WAITL(0); MFMA_M(1,0,3);
            PRIO0; SBAR;
            // P7; drain -> tile 2i+2 fully in LDS
            STB(1,2,c3); STB(1,3,c3);
            SBAR; PRIO1;
            MFMA_M(1,1,0); MFMA_M(1,1,1); MFMA_M(1,1,2); MFMA_M(1,1,3);
            PRIO0; DRAIN6; SBAR;
        }

        // epilogue: C/D layout col = lane&15, row = (lane>>4)*4 + reg
        float bias4[NR];
        #pragma unroll
        for (int ni = 0; ni < NR; ++ni)
            bias4[ni] = bias[n0 + wcol + ni * 16 + fr];
        #pragma unroll
        for (int mi = 0; mi < MR; ++mi) {
            #pragma unroll
            for (int ni = 0; ni < NR; ++ni) {
                const int col = n0 + wcol + ni * 16 + fr;
                const int rb  = m0 + wrow + mi * 16 + fq * 4;
                #pragma unroll
                for (int i2 = 0; i2 < 4; ++i2) {
                    float u  = acc[mi][ni][i2] + bias4[ni];
                    float uu = u * u;
                    float z  = u * __fmaf_rn(uu, -0.07135607f, -1.59576912f);
                    float e  = __expf(z);            // e^{-2s}
                    float g  = u * __builtin_amdgcn_rcpf(1.0f + e);
                    ((__hip_bfloat16*)C)[(size_t)(rb + i2) * N + col] =
                        __float2bfloat16(g);
                }
            }
        }
    } else {
        // ================= G1: 4-phase, lgkm ladder =================
        STA(0,0,0); STA(0,1,0); STA(0,2,0); STA(0,3,0);
        STB(0,0,0); STB(0,1,0);
        STB(1,0,1); STB(1,1,1);
        DRAIN2;
        __builtin_amdgcn_s_barrier();
        __builtin_amdgcn_sched_barrier(0);

        for (int i = 0; i < (KT >> 1); ++i) {
            const int t1 = 2 * i + 1;
            const int c2 = (2 * i + 2 < KT) ? 2 * i + 2 : KT - 1;
            const int c3 = (2 * i + 3 < KT) ? 2 * i + 3 : KT - 1;

            // P0: half0 of tile 2i. reads af0,af1,bfr0..3 (12);
            // stage buf1.A (tile 2i+1)
            RD_A1(0,0,0); RD_A1(0,0,1);
            RD_B1(0,0); RD_B1(0,1); RD_B1(0,2); RD_B1(0,3);
            STA(1,0,t1); STA(1,1,t1); STA(1,2,t1); STA(1,3,t1);
            SBAR; PRIO1;
            WAITL(6); MFMA1_N(0,0);
            WAITL(4); MFMA1_N(0,1);
            WAITL(2); MFMA1_N(0,2);
            WAITL(0); MFMA1_N(0,3);
            PRIO0; SBAR;
            // P1: half1. reads af0,af1 (4); stage buf0.B (tile 2i+2); drain(2)
            RD_A1(0,1,0); RD_A1(0,1,1);
            STB(0,0,c2); STB(0,1,c2);
            SBAR; PRIO1;
            WAITL(2); MFMA1_M(1,0);
            WAITL(0); MFMA1_M(1,1);
            PRIO0; DRAIN2; SBAR;
            // P2: half0 of tile 2i+1; stage buf0.A (tile 2i+2)
            RD_A1(1,0,0); RD_A1(1,0,1);
            RD_B1(1,0); RD_B1(1,1); RD_B1(1,2); RD_B1(1,3);
            STA(0,0,c2); STA(0,1,c2); STA(0,2,c2); STA(0,3,c2);
            SBAR; PRIO1;
            WAITL(6); MFMA1_N(0,0);
            WAITL(4); MFMA1_N(0,1);
            WAITL(2); MFMA1_N(0,2);
            WAITL(0); MFMA1_N(0,3);
            PRIO0; SBAR;
            // P3: half1; stage buf1.B (tile 2i+3); drain(2)
            RD_A1(1,1,0); RD_A1(1,1,1);
            STB(1,0,c3); STB(1,1,c3);
            SBAR; PRIO1;
            WAITL(2); MFMA1_M(1,0);
            WAITL(0); MFMA1_M(1,1);
            PRIO0; DRAIN2; SBAR;
        }

        // epilogue (swapped D): M = lane&15, N = (lane>>4)*4+reg -> float4
        const int mrow0 = m0 + wrow + fr;
        const int ncol0 = n0 + wcol + fq * 4;
        float4 b4[NR];
        #pragma unroll
        for (int ni = 0; ni < NR; ++ni)
            b4[ni] = *(const float4*)(bias + ncol0 + ni * 16);

        #pragma unroll
        for (int mi = 0; mi < MR; ++mi) {
            const int row = mrow0 + mi * 16;
            const float tw = tokw[row];
            #pragma unroll
            for (int ni = 0; ni < NR; ++ni) {
                f32x4 v = acc[mi][ni];
                float4 o;
                o.x = (v[0] + b4[ni].x) * tw;
                o.y = (v[1] + b4[ni].y) * tw;
                o.z = (v[2] + b4[ni].z) * tw;
                o.w = (v[3] + b4[ni].w) * tw;
                *(float4*)((float*)C + (size_t)row * N + ncol0 + ni * 16) = o;
            }
        }
    }

#undef STA
#undef STB
#undef RD_A1
#undef RD_B1
#undef MFMA_M
#undef MFMA_N
#undef MFMA1_N
#undef MFMA1_M
#undef SBAR
#undef WAITL
#undef PRIO1
#undef PRIO0
#undef DRAIN6
#undef DRAIN2
}

extern "C" void kernel_launch(void* const* d_in, const int* in_sizes, int n_in,
                              void* d_out, int out_size, void* d_ws, size_t ws_size,
                              hipStream_t stream)
{
    const float* x  = (const float*)d_in[0];
    const float* gW = (const float*)d_in[1];
    const float* gb = (const float*)d_in[2];
    const float* W1 = (const float*)d_in[3];
    const float* b1 = (const float*)d_in[4];
    const float* W2 = (const float*)d_in[5];
    const float* b2 = (const float*)d_in[6];
    float* out = (float*)d_out;

    char* ws = (char*)d_ws;
    __hip_bfloat16* xbf = (__hip_bfloat16*)ws;  ws += (size_t)Tn * Hn * 2;     // 16 MB
    __hip_bfloat16* W1t = (__hip_bfloat16*)ws;  ws += (size_t)Hn * DFFn * 2;   //  8 MB
    __hip_bfloat16* W2t = (__hip_bfloat16*)ws;  ws += (size_t)Hn * DFFn * 2;   //  8 MB
    __hip_bfloat16* hdd = (__hip_bfloat16*)ws;  ws += (size_t)Tn * DFFn * 2;   // 64 MB
    float* tokw     = (float*)ws;               ws += (size_t)Tn * 4;          // 32 KB
    float* load_sum = (float*)ws;               ws += En * 4;
    int*   counts   = (int*)ws;                 ws += En * 4;

    static bool attr_done = false;
    if (!attr_done) {
        (void)hipFuncSetAttribute(
            reinterpret_cast<const void*>(&gemm8<256, 2, 4, 0>),
            hipFuncAttributeMaxDynamicSharedMemorySize, 131072);
        (void)hipFuncSetAttribute(
            reinterpret_cast<const void*>(&gemm8<128, 4, 2, 1>),
            hipFuncAttributeMaxDynamicSharedMemorySize, 98304);
        attr_done = true;
    }

    hipMemsetAsync(load_sum, 0, En * 4 * 2, stream);   // load_sum + counts

    // 512 fat transpose blocks + 1024 gate blocks
    prep<<<1536, 256, 0, stream>>>(W1, (unsigned short*)W1t,
                                   W2, (unsigned short*)W2t,
                                   x, gW, gb, (unsigned short*)xbf,
                                   tokw, load_sum, counts);

    // hdd = gelu(x @ W1 + b1): M=8192, N=4096, K=1024; 32x16 = 512 tiles
    gemm8<256, 2, 4, 0><<<513, 512, 131072, stream>>>(
        xbf, W1t, b1, nullptr, hdd, DFFn, Hn, 16,
        load_sum, counts, out + (size_t)Tn * Hn, 512);

    // out = (hdd @ W2 + b2) * tokw: M=8192, N=1024, K=4096; 32x8 = 256 blocks
    gemm8<128, 4, 2, 1><<<256, 512, 98304, stream>>>(
        hdd, W2t, b2, tokw, out, Hn, DFFn, 8,
        nullptr, nullptr, nullptr, 256);
}